// Round 1
// baseline (290.948 us; speedup 1.0000x reference)
//
#include <hip/hip_runtime.h>
#include <stdint.h>

#define BB 4
#define TT 2048
#define HH 1024
#define NN 16
#define KK 1024           // GEMM K  (= H)
#define GG 1024           // GEMM out cols (= H)
#define MM (BB*TT)        // GEMM rows

typedef __attribute__((ext_vector_type(8))) short short8;
typedef __attribute__((ext_vector_type(4))) float f32x4;

__device__ __forceinline__ unsigned short f2bf(float f) {
  union { float f; unsigned u; } a; a.f = f;
  unsigned u = a.u;
  u += 0x7fffu + ((u >> 16) & 1u);   // round-to-nearest-even
  return (unsigned short)(u >> 16);
}

__global__ __launch_bounds__(256) void cvt_f32_bf16(const float* __restrict__ src,
                                                    unsigned short* __restrict__ dst, int n4) {
  int i = blockIdx.x * blockDim.x + threadIdx.x;
  if (i >= n4) return;
  float4 a = ((const float4*)src)[i];
  ushort4 o;
  o.x = f2bf(a.x); o.y = f2bf(a.y); o.z = f2bf(a.z); o.w = f2bf(a.w);
  ((ushort4*)dst)[i] = o;
}

// dt[m,g] = softplus( sum_k x[m,k]*W[g,k] + b_dt[g] )
// m97-style: 128x128 block tile, BK=32, 4 waves of 64x64, global_load_lds width 16.
__global__ __launch_bounds__(256) void gemm_dt(const unsigned short* __restrict__ xb,
                                               const unsigned short* __restrict__ wb,
                                               const float* __restrict__ b_dt,
                                               float* __restrict__ dt) {
  __shared__ short lsA[128 * 32];
  __shared__ short lsB[128 * 32];
  const int tid  = threadIdx.x;
  const int w    = tid >> 6;
  const int lane = tid & 63;
  const int m0 = blockIdx.x * 128;
  const int g0 = blockIdx.y * 128;

  // staging: wave w, instr q in {0,1}: LDS elements [w*1024 + q*512 + lane*8, +8)
  const int e0  = w * 1024 + lane * 8;
  const int am0 = e0 >> 5,        ak0 = e0 & 31;
  const int am1 = (e0 + 512) >> 5, ak1 = (e0 + 512) & 31;
  const unsigned short* gA0 = xb + (size_t)(m0 + am0) * KK + ak0;
  const unsigned short* gA1 = xb + (size_t)(m0 + am1) * KK + ak1;
  const unsigned short* gB0 = wb + (size_t)(g0 + am0) * KK + ak0;
  const unsigned short* gB1 = wb + (size_t)(g0 + am1) * KK + ak1;
  short* lA0 = lsA + w * 1024;
  short* lB0 = lsB + w * 1024;

  const int wm   = (w >> 1) * 64;    // wave tile: 64x64
  const int wg   = (w & 1) * 64;
  const int lrow = lane & 15;
  const int lq   = lane >> 4;

  f32x4 acc[4][4];
  const f32x4 zero = {0.f, 0.f, 0.f, 0.f};
#pragma unroll
  for (int i = 0; i < 4; ++i)
#pragma unroll
    for (int j = 0; j < 4; ++j) acc[i][j] = zero;

  for (int kt = 0; kt < KK / 32; ++kt) {
    const int ko = kt * 32;
    __builtin_amdgcn_global_load_lds((__attribute__((address_space(1))) void*)(gA0 + ko),
                                     (__attribute__((address_space(3))) void*)(lA0), 16, 0, 0);
    __builtin_amdgcn_global_load_lds((__attribute__((address_space(1))) void*)(gA1 + ko),
                                     (__attribute__((address_space(3))) void*)(lA0 + 512), 16, 0, 0);
    __builtin_amdgcn_global_load_lds((__attribute__((address_space(1))) void*)(gB0 + ko),
                                     (__attribute__((address_space(3))) void*)(lB0), 16, 0, 0);
    __builtin_amdgcn_global_load_lds((__attribute__((address_space(1))) void*)(gB1 + ko),
                                     (__attribute__((address_space(3))) void*)(lB0 + 512), 16, 0, 0);
    __syncthreads();

    short8 af[4], bfr[4];
#pragma unroll
    for (int mi = 0; mi < 4; ++mi)
      af[mi] = *(const short8*)&lsA[(wm + mi * 16 + lrow) * 32 + lq * 8];
#pragma unroll
    for (int ni = 0; ni < 4; ++ni)
      bfr[ni] = *(const short8*)&lsB[(wg + ni * 16 + lrow) * 32 + lq * 8];
#pragma unroll
    for (int mi = 0; mi < 4; ++mi)
#pragma unroll
      for (int ni = 0; ni < 4; ++ni)
        acc[mi][ni] = __builtin_amdgcn_mfma_f32_16x16x32_bf16(af[mi], bfr[ni], acc[mi][ni], 0, 0, 0);
    __syncthreads();
  }

#pragma unroll
  for (int mi = 0; mi < 4; ++mi)
#pragma unroll
    for (int ni = 0; ni < 4; ++ni) {
      const int gcol = g0 + wg + ni * 16 + lrow;
      const float bias = b_dt[gcol];
#pragma unroll
      for (int r = 0; r < 4; ++r) {
        const int mrow = m0 + wm + mi * 16 + lq * 4 + r;
        float z = acc[mi][ni][r] + bias;
        float sp = (z > 15.f) ? z : log1pf(__expf(z));
        dt[(size_t)mrow * GG + gcol] = sp;
      }
    }
}

// butterfly reduce-scatter over the 16-lane group: lane n ends with sum_p v_p[n]
__device__ __forceinline__ float reduce16(float (&v)[16], int n16) {
#pragma unroll
  for (int i = 0; i < 8; ++i) {
    float lo = v[i], hi = v[i + 8];
    float snd = (n16 & 8) ? lo : hi;
    float rcv = __shfl_xor(snd, 8);
    v[i] = ((n16 & 8) ? hi : lo) + rcv;
  }
#pragma unroll
  for (int i = 0; i < 4; ++i) {
    float lo = v[i], hi = v[i + 4];
    float snd = (n16 & 4) ? lo : hi;
    float rcv = __shfl_xor(snd, 4);
    v[i] = ((n16 & 4) ? hi : lo) + rcv;
  }
#pragma unroll
  for (int i = 0; i < 2; ++i) {
    float lo = v[i], hi = v[i + 2];
    float snd = (n16 & 2) ? lo : hi;
    float rcv = __shfl_xor(snd, 2);
    v[i] = ((n16 & 2) ? hi : lo) + rcv;
  }
  float lo = v[0], hi = v[1];
  float snd = (n16 & 1) ? lo : hi;
  float rcv = __shfl_xor(snd, 1);
  return ((n16 & 1) ? hi : lo) + rcv;
}

__device__ __forceinline__ void load_chunk(const float* __restrict__ dp, const float* __restrict__ up,
                                           int c, float (&dd)[16], float (&uu)[16]) {
  const float* pd = dp + (size_t)c * 16 * HH;
  const float* pu = up + (size_t)c * 16 * HH;
#pragma unroll
  for (int j = 0; j < 16; ++j) {
    dd[j] = pd[(size_t)j * HH];
    uu[j] = pu[(size_t)j * HH];
  }
}

__device__ __forceinline__ void compute_chunk(float& s, const float (&dd)[16], const float (&uu)[16],
                                              float Aneg, float Bm, float Cc, float Dv,
                                              int n16, float* __restrict__ op, int c) {
  float v[16];
#pragma unroll
  for (int j = 0; j < 16; ++j) {
    float dtv = dd[j], uv = uu[j];
    float ab = __expf(dtv * Aneg);
    s = fmaf(ab, s, (dtv * uv) * Bm);
    float rr = Cc * s;
    rr += (n16 == 0) ? Dv * uv : 0.f;
    v[j] = rr;
  }
  float y = reduce16(v, n16);
  op[(size_t)(c * 16 + n16) * HH] = y;
}

__global__ __launch_bounds__(256) void ssm_scan(const float* __restrict__ x,
                                                const float* __restrict__ dt,
                                                const float* __restrict__ A_log,
                                                const float* __restrict__ Bm_,
                                                const float* __restrict__ Cm_,
                                                const float* __restrict__ Dv_,
                                                float* __restrict__ out,
                                                float* __restrict__ stateOut) {
  const int tid = threadIdx.x;
  const int g   = tid >> 4;
  const int n16 = tid & 15;
  const int b   = blockIdx.x >> 6;
  const int h   = ((blockIdx.x & 63) << 4) + g;

  const float Aneg = -__expf(A_log[h * NN + n16]);
  const float Bm   = Bm_[h * NN + n16];
  const float Cc   = Cm_[h * NN + n16];
  const float Dv   = Dv_[h];

  const size_t base = (size_t)b * TT * HH + h;
  const float* up = x  + base;
  const float* dp = dt + base;
  float*       op = out + base;

  float s = 0.f;
  float d0[16], u0[16], d1[16], u1[16];
  const int NC = TT / 16;   // 128, even

  load_chunk(dp, up, 0, d0, u0);
#pragma unroll 1
  for (int c = 0; c < NC; c += 2) {
    load_chunk(dp, up, c + 1, d1, u1);
    compute_chunk(s, d0, u0, Aneg, Bm, Cc, Dv, n16, op, c);
    if (c + 2 < NC) load_chunk(dp, up, c + 2, d0, u0);
    compute_chunk(s, d1, u1, Aneg, Bm, Cc, Dv, n16, op, c + 1);
  }

  stateOut[((size_t)b * HH + h) * NN + n16] = s;
}

extern "C" void kernel_launch(void* const* d_in, const int* in_sizes, int n_in,
                              void* d_out, int out_size, void* d_ws, size_t ws_size,
                              hipStream_t stream) {
  const float* x     = (const float*)d_in[0];
  const float* A_log = (const float*)d_in[1];
  const float* B_mat = (const float*)d_in[2];
  const float* C_mat = (const float*)d_in[3];
  const float* D_vec = (const float*)d_in[4];
  const float* W_dt  = (const float*)d_in[5];
  const float* b_dt  = (const float*)d_in[6];
  float* out = (float*)d_out;

  char* ws = (char*)d_ws;
  unsigned short* xb = (unsigned short*)(ws);                 // 16 MB
  unsigned short* wb = (unsigned short*)(ws + 16777216);      //  2 MB
  float*          dt = (float*)(ws + 18874368);               // 32 MB
  float* stateOut = out + (size_t)BB * TT * HH;

  cvt_f32_bf16<<<(MM * KK / 4 + 255) / 256, 256, 0, stream>>>(x, xb, MM * KK / 4);
  cvt_f32_bf16<<<(GG * KK / 4 + 255) / 256, 256, 0, stream>>>(W_dt, wb, GG * KK / 4);
  gemm_dt<<<dim3(MM / 128, GG / 128), 256, 0, stream>>>(xb, wb, b_dt, dt);
  ssm_scan<<<BB * HH / 16, 256, 0, stream>>>(x, dt, A_log, B_mat, C_mat, D_vec, out, stateOut);
}

// Round 2
// 251.322 us; speedup vs baseline: 1.1577x; 1.1577x over previous
//
#include <hip/hip_runtime.h>
#include <stdint.h>

#define BB 4
#define TT 2048
#define HH 1024
#define NN 16
#define KK 1024           // GEMM K  (= H)
#define GG 1024           // GEMM out cols (= H)
#define MM (BB*TT)        // GEMM rows
#define NCHUNK 16
#define TC (TT/NCHUNK)    // 128 timesteps per chunk

typedef __attribute__((ext_vector_type(8))) short short8;
typedef __attribute__((ext_vector_type(4))) float f32x4;

__device__ __forceinline__ unsigned short f2bf(float f) {
  union { float f; unsigned u; } a; a.f = f;
  unsigned u = a.u;
  u += 0x7fffu + ((u >> 16) & 1u);   // round-to-nearest-even
  return (unsigned short)(u >> 16);
}

__global__ __launch_bounds__(256) void cvt_f32_bf16(const float* __restrict__ src,
                                                    unsigned short* __restrict__ dst, int n4) {
  int i = blockIdx.x * blockDim.x + threadIdx.x;
  if (i >= n4) return;
  float4 a = ((const float4*)src)[i];
  ushort4 o;
  o.x = f2bf(a.x); o.y = f2bf(a.y); o.z = f2bf(a.z); o.w = f2bf(a.w);
  ((ushort4*)dst)[i] = o;
}

// dt[m,g] = softplus( sum_k x[m,k]*W[g,k] + b_dt[g] )
__global__ __launch_bounds__(256) void gemm_dt(const unsigned short* __restrict__ xb,
                                               const unsigned short* __restrict__ wb,
                                               const float* __restrict__ b_dt,
                                               float* __restrict__ dt) {
  __shared__ short lsA[128 * 32];
  __shared__ short lsB[128 * 32];
  const int tid  = threadIdx.x;
  const int w    = tid >> 6;
  const int lane = tid & 63;
  const int m0 = blockIdx.x * 128;
  const int g0 = blockIdx.y * 128;

  const int e0  = w * 1024 + lane * 8;
  const int am0 = e0 >> 5,        ak0 = e0 & 31;
  const int am1 = (e0 + 512) >> 5, ak1 = (e0 + 512) & 31;
  const unsigned short* gA0 = xb + (size_t)(m0 + am0) * KK + ak0;
  const unsigned short* gA1 = xb + (size_t)(m0 + am1) * KK + ak1;
  const unsigned short* gB0 = wb + (size_t)(g0 + am0) * KK + ak0;
  const unsigned short* gB1 = wb + (size_t)(g0 + am1) * KK + ak1;
  short* lA0 = lsA + w * 1024;
  short* lB0 = lsB + w * 1024;

  const int wm   = (w >> 1) * 64;
  const int wg   = (w & 1) * 64;
  const int lrow = lane & 15;
  const int lq   = lane >> 4;

  f32x4 acc[4][4];
  const f32x4 zero = {0.f, 0.f, 0.f, 0.f};
#pragma unroll
  for (int i = 0; i < 4; ++i)
#pragma unroll
    for (int j = 0; j < 4; ++j) acc[i][j] = zero;

  for (int kt = 0; kt < KK / 32; ++kt) {
    const int ko = kt * 32;
    __builtin_amdgcn_global_load_lds((__attribute__((address_space(1))) void*)(gA0 + ko),
                                     (__attribute__((address_space(3))) void*)(lA0), 16, 0, 0);
    __builtin_amdgcn_global_load_lds((__attribute__((address_space(1))) void*)(gA1 + ko),
                                     (__attribute__((address_space(3))) void*)(lA0 + 512), 16, 0, 0);
    __builtin_amdgcn_global_load_lds((__attribute__((address_space(1))) void*)(gB0 + ko),
                                     (__attribute__((address_space(3))) void*)(lB0), 16, 0, 0);
    __builtin_amdgcn_global_load_lds((__attribute__((address_space(1))) void*)(gB1 + ko),
                                     (__attribute__((address_space(3))) void*)(lB0 + 512), 16, 0, 0);
    __syncthreads();

    short8 af[4], bfr[4];
#pragma unroll
    for (int mi = 0; mi < 4; ++mi)
      af[mi] = *(const short8*)&lsA[(wm + mi * 16 + lrow) * 32 + lq * 8];
#pragma unroll
    for (int ni = 0; ni < 4; ++ni)
      bfr[ni] = *(const short8*)&lsB[(wg + ni * 16 + lrow) * 32 + lq * 8];
#pragma unroll
    for (int mi = 0; mi < 4; ++mi)
#pragma unroll
      for (int ni = 0; ni < 4; ++ni)
        acc[mi][ni] = __builtin_amdgcn_mfma_f32_16x16x32_bf16(af[mi], bfr[ni], acc[mi][ni], 0, 0, 0);
    __syncthreads();
  }

#pragma unroll
  for (int mi = 0; mi < 4; ++mi)
#pragma unroll
    for (int ni = 0; ni < 4; ++ni) {
      const int gcol = g0 + wg + ni * 16 + lrow;
      const float bias = b_dt[gcol];
#pragma unroll
      for (int r = 0; r < 4; ++r) {
        const int mrow = m0 + wm + mi * 16 + lq * 4 + r;
        float z = acc[mi][ni][r] + bias;
        float sp = (z > 15.f) ? z : log1pf(__expf(z));
        dt[(size_t)mrow * GG + gcol] = sp;
      }
    }
}

// butterfly reduce-scatter over the 16-lane group: lane n ends with sum_p v_p[n]
__device__ __forceinline__ float reduce16(float (&v)[16], int n16) {
#pragma unroll
  for (int i = 0; i < 8; ++i) {
    float lo = v[i], hi = v[i + 8];
    float snd = (n16 & 8) ? lo : hi;
    float rcv = __shfl_xor(snd, 8);
    v[i] = ((n16 & 8) ? hi : lo) + rcv;
  }
#pragma unroll
  for (int i = 0; i < 4; ++i) {
    float lo = v[i], hi = v[i + 4];
    float snd = (n16 & 4) ? lo : hi;
    float rcv = __shfl_xor(snd, 4);
    v[i] = ((n16 & 4) ? hi : lo) + rcv;
  }
#pragma unroll
  for (int i = 0; i < 2; ++i) {
    float lo = v[i], hi = v[i + 2];
    float snd = (n16 & 2) ? lo : hi;
    float rcv = __shfl_xor(snd, 2);
    v[i] = ((n16 & 2) ? hi : lo) + rcv;
  }
  float lo = v[0], hi = v[1];
  float snd = (n16 & 1) ? lo : hi;
  float rcv = __shfl_xor(snd, 1);
  return ((n16 & 1) ? hi : lo) + rcv;
}

__device__ __forceinline__ void load_chunk(const float* __restrict__ dp, const float* __restrict__ up,
                                           int c, float (&dd)[16], float (&uu)[16]) {
  const float* pd = dp + (size_t)c * 16 * HH;
  const float* pu = up + (size_t)c * 16 * HH;
#pragma unroll
  for (int j = 0; j < 16; ++j) {
    dd[j] = pd[(size_t)j * HH];
    uu[j] = pu[(size_t)j * HH];
  }
}

__device__ __forceinline__ void compute_chunk(float& s, const float (&dd)[16], const float (&uu)[16],
                                              float Aneg, float Bm, float Cc, float Dv,
                                              int n16, float* __restrict__ op, int c) {
  float v[16];
#pragma unroll
  for (int j = 0; j < 16; ++j) {
    float dtv = dd[j], uv = uu[j];
    float ab = __expf(dtv * Aneg);
    s = fmaf(ab, s, (dtv * uv) * Bm);
    float rr = Cc * s;
    rr += (n16 == 0) ? Dv * uv : 0.f;
    v[j] = rr;
  }
  float y = reduce16(v, n16);
  op[(size_t)(c * 16 + n16) * HH] = y;
}

// ---- chunk-parallel scan -------------------------------------------------
// block: 256 threads = 16 h-groups x 16 n. grid: 64 h-tiles x 4 b x NCHUNK c.
// phase 1: per-chunk local state (from 0) + chunk decay exp(Aneg*sum_dt)
__global__ __launch_bounds__(256) void ssm_phase1(const float* __restrict__ x,
                                                  const float* __restrict__ dt,
                                                  const float* __restrict__ A_log,
                                                  const float* __restrict__ Bm_,
                                                  float* __restrict__ sloc,
                                                  float* __restrict__ decay) {
  const int tid = threadIdx.x;
  const int g   = tid >> 4;
  const int n16 = tid & 15;
  const int bid = blockIdx.x;
  const int ht  = bid & 63;
  const int b   = (bid >> 6) & 3;
  const int c   = bid >> 8;
  const int h   = (ht << 4) + g;

  const float Aneg = -__expf(A_log[h * NN + n16]);
  const float Bm   = Bm_[h * NN + n16];

  const size_t base = (size_t)b * TT * HH + (size_t)c * TC * HH + h;
  const float* up = x  + base;
  const float* dp = dt + base;

  float s = 0.f, sd = 0.f;
  float d0[16], u0[16], d1[16], u1[16];
  const int NC = TC / 16;   // 8

  load_chunk(dp, up, 0, d0, u0);
#pragma unroll 1
  for (int cc = 0; cc < NC; cc += 2) {
    load_chunk(dp, up, cc + 1, d1, u1);
#pragma unroll
    for (int j = 0; j < 16; ++j) {
      float ab = __expf(d0[j] * Aneg);
      s = fmaf(ab, s, (d0[j] * u0[j]) * Bm);
      sd += d0[j];
    }
    if (cc + 2 < NC) load_chunk(dp, up, cc + 2, d0, u0);
#pragma unroll
    for (int j = 0; j < 16; ++j) {
      float ab = __expf(d1[j] * Aneg);
      s = fmaf(ab, s, (d1[j] * u1[j]) * Bm);
      sd += d1[j];
    }
  }

  const size_t idx = (((size_t)c * BB + b) * HH + h) * NN + n16;
  sloc[idx]  = s;
  decay[idx] = __expf(Aneg * sd);
}

// phase 2: sequential combine over chunks; writes carry-in per chunk in place
// (sloc becomes carry-in) and final state to stateOut.
__global__ __launch_bounds__(256) void ssm_phase2(float* __restrict__ sloc,
                                                  const float* __restrict__ decay,
                                                  float* __restrict__ stateOut) {
  const int id = blockIdx.x * 256 + threadIdx.x;   // (b,h,n) flat, 65536
  float carry = 0.f;
#pragma unroll
  for (int c = 0; c < NCHUNK; ++c) {
    const size_t idx = (size_t)c * (BB * HH * NN) + id;
    const float sl = sloc[idx];
    const float dc = decay[idx];
    sloc[idx] = carry;
    carry = fmaf(dc, carry, sl);
  }
  stateOut[id] = carry;
}

// phase 3: scan each chunk from its carry-in, emitting y.
__global__ __launch_bounds__(256) void ssm_phase3(const float* __restrict__ x,
                                                  const float* __restrict__ dt,
                                                  const float* __restrict__ A_log,
                                                  const float* __restrict__ Bm_,
                                                  const float* __restrict__ Cm_,
                                                  const float* __restrict__ Dv_,
                                                  const float* __restrict__ carryBuf,
                                                  float* __restrict__ out) {
  const int tid = threadIdx.x;
  const int g   = tid >> 4;
  const int n16 = tid & 15;
  const int bid = blockIdx.x;
  const int ht  = bid & 63;
  const int b   = (bid >> 6) & 3;
  const int c   = bid >> 8;
  const int h   = (ht << 4) + g;

  const float Aneg = -__expf(A_log[h * NN + n16]);
  const float Bm   = Bm_[h * NN + n16];
  const float Cc   = Cm_[h * NN + n16];
  const float Dv   = Dv_[h];

  const size_t base = (size_t)b * TT * HH + (size_t)c * TC * HH + h;
  const float* up = x  + base;
  const float* dp = dt + base;
  float*       op = out + base;

  float s = carryBuf[(((size_t)c * BB + b) * HH + h) * NN + n16];
  float d0[16], u0[16], d1[16], u1[16];
  const int NC = TC / 16;   // 8

  load_chunk(dp, up, 0, d0, u0);
#pragma unroll 1
  for (int cc = 0; cc < NC; cc += 2) {
    load_chunk(dp, up, cc + 1, d1, u1);
    compute_chunk(s, d0, u0, Aneg, Bm, Cc, Dv, n16, op, cc);
    if (cc + 2 < NC) load_chunk(dp, up, cc + 2, d0, u0);
    compute_chunk(s, d1, u1, Aneg, Bm, Cc, Dv, n16, op, cc + 1);
  }
}

extern "C" void kernel_launch(void* const* d_in, const int* in_sizes, int n_in,
                              void* d_out, int out_size, void* d_ws, size_t ws_size,
                              hipStream_t stream) {
  const float* x     = (const float*)d_in[0];
  const float* A_log = (const float*)d_in[1];
  const float* B_mat = (const float*)d_in[2];
  const float* C_mat = (const float*)d_in[3];
  const float* D_vec = (const float*)d_in[4];
  const float* W_dt  = (const float*)d_in[5];
  const float* b_dt  = (const float*)d_in[6];
  float* out = (float*)d_out;

  char* ws = (char*)d_ws;
  unsigned short* xb = (unsigned short*)(ws);                 // 16 MB (dead after gemm)
  unsigned short* wb = (unsigned short*)(ws + 16777216);      //  2 MB (dead after gemm)
  float*          dt = (float*)(ws + 18874368);               // 32 MB
  // sloc/decay reuse the xb region: gemm completes before phase1 in stream order.
  float*          sloc  = (float*)(ws);                       // 4 MB
  float*          decay = (float*)(ws + 4194304);             // 4 MB
  float* stateOut = out + (size_t)BB * TT * HH;

  cvt_f32_bf16<<<(MM * KK / 4 + 255) / 256, 256, 0, stream>>>(x, xb, MM * KK / 4);
  cvt_f32_bf16<<<(GG * KK / 4 + 255) / 256, 256, 0, stream>>>(W_dt, wb, GG * KK / 4);
  gemm_dt<<<dim3(MM / 128, GG / 128), 256, 0, stream>>>(xb, wb, b_dt, dt);

  const int nblk = BB * (HH / 16) * NCHUNK;   // 4096
  ssm_phase1<<<nblk, 256, 0, stream>>>(x, dt, A_log, B_mat, sloc, decay);
  ssm_phase2<<<(BB * HH * NN) / 256, 256, 0, stream>>>(sloc, decay, stateOut);
  ssm_phase3<<<nblk, 256, 0, stream>>>(x, dt, A_log, B_mat, C_mat, D_vec, sloc, out);
}